// Round 18
// baseline (982.159 us; speedup 1.0000x reference)
//
#include <hip/hip_runtime.h>

// B=1024, T=128, LAT=128, HODE=128, HID=256, OUT=128, NC=2, H=64.
// d_out = xs [128,1024,128] f32 ++ lstm_out [1024,2] f32.
//
// Structure (R18):
//   ode  : RK4 chains, TWO independent 16-row groups per block interleaved
//          (dual-chain ILP hides per-chain latency; shared barriers).
//          Per-step bf16 y export (zbuf) + fused XW epilogue (32 t's/block).
//   wf   : fuse l2h*h2o -> Wf (bf16) + bfused  (overlaps ode)
//   proj_lstm : block 0 = 4-wave LSTM chain (DPP gather); blocks 1..2048 = proj
//   fc2  : tiny epilogue

typedef short s16x8 __attribute__((ext_vector_type(8)));
typedef float f32x4 __attribute__((ext_vector_type(4)));
typedef _Float16 f16x2 __attribute__((ext_vector_type(2)));
typedef _Float16 f16x8 __attribute__((ext_vector_type(8)));

#define MFMA16(a, b, c) __builtin_amdgcn_mfma_f32_16x16x32_bf16((a), (b), (c), 0, 0, 0)

// Barrier that waits only on LDS ops (lgkmcnt), NOT vmcnt (keeps global ops in flight).
__device__ __forceinline__ void lds_barrier() {
  asm volatile("s_waitcnt lgkmcnt(0)\n\ts_barrier" ::: "memory");
}

__device__ __forceinline__ unsigned short f2bf(float x) {
  union { float f; unsigned u; } v; v.f = x;
  return (unsigned short)((v.u + 0x7FFFu + ((v.u >> 16) & 1u)) >> 16);  // RNE
}

// Pack 2 f32 -> 2 bf16 in one dword (RNE; bit-identical to f2bf for finite vals).
__device__ __forceinline__ unsigned cvtpk(float lo, float hi) {
  unsigned r;
  asm("v_cvt_pk_bf16_f32 %0, %1, %2" : "=v"(r) : "v"(lo), "v"(hi));
  return r;
}

// Nibble-XOR swizzled LDS byte offset for a [16][128] bf16 tile (row stride 256B).
__device__ __forceinline__ int swz(int row, int col2) {
  return row * 256 + (col2 ^ ((row & 15) << 4));
}

__device__ __forceinline__ f16x8 cvt8(const float* p) {
  float4 a = *(const float4*)p, b = *(const float4*)(p + 4);
  return (f16x8){(_Float16)a.x, (_Float16)a.y, (_Float16)a.z, (_Float16)a.w,
                 (_Float16)b.x, (_Float16)b.y, (_Float16)b.z, (_Float16)b.w};
}

// ---------------------------------------------------------------------------
// Kernel 1: RK4 ODE. 32 blocks x 32 rows (2 groups x 16), 256 thr (4 waves).
// ---------------------------------------------------------------------------
__global__ __launch_bounds__(256, 1) void ode_kernel(
    const float* __restrict__ init, const float* __restrict__ ts,
    const float* __restrict__ w1, const float* __restrict__ b1,
    const float* __restrict__ w2, const float* __restrict__ b2,
    const float* __restrict__ wih, const float* __restrict__ bih,
    const float* __restrict__ bhh,
    unsigned short* __restrict__ zbuf, float* __restrict__ XW4)
{
  __shared__ __align__(16) unsigned char sY[2][4096];  // 2 x (16 x 128 bf16), swizzled
  __shared__ __align__(16) unsigned char sH[2][4096];
  __shared__ __align__(16) float sYf[4096];            // 32 x 128 f32 (XW epilogue)
  const int tid = (int)threadIdx.x;
  const int w = tid >> 6, lane = tid & 63;
  const int l15 = lane & 15, l4 = lane >> 4;
  const int rowbase = (int)blockIdx.x * 32;
  const int colbase = w * 32;

  s16x8 w1f[2][4], w2f[2][4];
#pragma unroll
  for (int tc = 0; tc < 2; ++tc) {
    const int rj = colbase + 16 * tc + l15;
#pragma unroll
    for (int ks = 0; ks < 4; ++ks) {
      const int kb = ks * 32 + l4 * 8;
      s16x8 va, vb;
#pragma unroll
      for (int t = 0; t < 8; ++t) {
        va[t] = (short)f2bf(w1[rj * 128 + kb + t]);
        vb[t] = (short)f2bf(w2[rj * 128 + kb + t]);
      }
      w1f[tc][ks] = va; w2f[tc][ks] = vb;
    }
  }
  float b1v[2], b2v[2];
#pragma unroll
  for (int tc = 0; tc < 2; ++tc) {
    const int cc = colbase + 16 * tc + l15;
    b1v[tc] = b1[cc]; b2v[tc] = b2[cc];
  }

  int aOff[4];
#pragma unroll
  for (int ks = 0; ks < 4; ++ks) aOff[ks] = swz(l15, (ks * 32 + l4 * 8) * 2);
  int cOff[2][4];
#pragma unroll
  for (int tc = 0; tc < 2; ++tc)
#pragma unroll
    for (int r = 0; r < 4; ++r)
      cOff[tc][r] = swz(l4 * 4 + r, (colbase + 16 * tc + l15) * 2);

  // per-group f32 state (g loop always fully unrolled -> registers)
  float y0[2][2][4], yac[2][2][4];
#pragma unroll
  for (int g = 0; g < 2; ++g)
#pragma unroll
    for (int tc = 0; tc < 2; ++tc)
#pragma unroll
      for (int r = 0; r < 4; ++r)
        y0[g][tc][r] = init[(rowbase + g * 16 + l4 * 4 + r) * 128 + colbase + 16 * tc + l15];

  {  // stage initial y into sY + export zs slice 0 (both groups)
    const int i = tid * 8;
    const int row = i >> 7, col = i & 127;
#pragma unroll
    for (int g = 0; g < 2; ++g) {
      union { unsigned short u[8]; s16x8 v; } p;
#pragma unroll
      for (int t = 0; t < 8; ++t)
        p.u[t] = f2bf(init[(rowbase + g * 16 + row) * 128 + col + t]);
      *(s16x8*)(sY[g] + swz(row, col * 2)) = p.v;
      *(s16x8*)(zbuf + (rowbase + g * 16) * 128 + i) = p.v;
    }
  }
  __syncthreads();

  const f32x4 fz = {0.f, 0.f, 0.f, 0.f};
  float t_cur = ts[0], t_next = ts[1];

  for (int s = 0; s < 127; ++s) {
    const float t_next2 = (s < 126) ? ts[s + 2] : 0.f;
    const float dt = t_next - t_cur;
    const float c16 = dt * (1.f / 6.f), c13 = dt * (1.f / 3.f), ch = dt * 0.5f;
#pragma unroll
    for (int st = 0; st < 4; ++st) {
      // ---- GEMM1 both groups, interleaved issue (B hides A's latency) ----
      s16x8 aA[4], aB[4];
#pragma unroll
      for (int ks = 0; ks < 4; ++ks) {
        aA[ks] = *(const s16x8*)(sY[0] + aOff[ks]);
        aB[ks] = *(const s16x8*)(sY[1] + aOff[ks]);
      }
      f32x4 accA[2], accB[2];
      {
        const f32x4 pA0 = MFMA16(aA[1], w1f[0][1], MFMA16(aA[0], w1f[0][0], fz));
        const f32x4 qA0 = MFMA16(aB[1], w1f[0][1], MFMA16(aB[0], w1f[0][0], fz));
        const f32x4 pA1 = MFMA16(aA[1], w1f[1][1], MFMA16(aA[0], w1f[1][0], fz));
        const f32x4 qA1 = MFMA16(aB[1], w1f[1][1], MFMA16(aB[0], w1f[1][0], fz));
        const f32x4 pB0 = MFMA16(aA[3], w1f[0][3], MFMA16(aA[2], w1f[0][2], fz));
        const f32x4 qB0 = MFMA16(aB[3], w1f[0][3], MFMA16(aB[2], w1f[0][2], fz));
        const f32x4 pB1 = MFMA16(aA[3], w1f[1][3], MFMA16(aA[2], w1f[1][2], fz));
        const f32x4 qB1 = MFMA16(aB[3], w1f[1][3], MFMA16(aB[2], w1f[1][2], fz));
        accA[0] = pA0 + pB0; accA[1] = pA1 + pB1;
        accB[0] = qA0 + qB0; accB[1] = qA1 + qB1;
      }
#pragma unroll
      for (int g = 0; g < 2; ++g) {
        const f32x4* ac = (g == 0) ? accA : accB;
#pragma unroll
        for (int r = 0; r < 4; ++r) {
          float v0 = ac[0][r] + b1v[0];
          float v1 = ac[1][r] + b1v[1];
          v0 = v0 > 0.f ? v0 : (__expf(v0) - 1.f);  // ELU (alpha=1)
          v1 = v1 > 0.f ? v1 : (__expf(v1) - 1.f);
          const unsigned p = cvtpk(v0, v1);
          *(unsigned short*)(sH[g] + cOff[0][r]) = (unsigned short)p;
          *(unsigned short*)(sH[g] + cOff[1][r]) = (unsigned short)(p >> 16);
        }
      }
      lds_barrier();
      // ---- GEMM2 both groups ----
      s16x8 hA[4], hB[4];
#pragma unroll
      for (int ks = 0; ks < 4; ++ks) {
        hA[ks] = *(const s16x8*)(sH[0] + aOff[ks]);
        hB[ks] = *(const s16x8*)(sH[1] + aOff[ks]);
      }
      f32x4 kcA[2], kcB[2];
      {
        const f32x4 pA0 = MFMA16(hA[1], w2f[0][1], MFMA16(hA[0], w2f[0][0], fz));
        const f32x4 qA0 = MFMA16(hB[1], w2f[0][1], MFMA16(hB[0], w2f[0][0], fz));
        const f32x4 pA1 = MFMA16(hA[1], w2f[1][1], MFMA16(hA[0], w2f[1][0], fz));
        const f32x4 qA1 = MFMA16(hB[1], w2f[1][1], MFMA16(hB[0], w2f[1][0], fz));
        const f32x4 pB0 = MFMA16(hA[3], w2f[0][3], MFMA16(hA[2], w2f[0][2], fz));
        const f32x4 qB0 = MFMA16(hB[3], w2f[0][3], MFMA16(hB[2], w2f[0][2], fz));
        const f32x4 pB1 = MFMA16(hA[3], w2f[1][3], MFMA16(hA[2], w2f[1][2], fz));
        const f32x4 qB1 = MFMA16(hB[3], w2f[1][3], MFMA16(hB[2], w2f[1][2], fz));
        kcA[0] = pA0 + pB0; kcA[1] = pA1 + pB1;
        kcB[0] = qA0 + qB0; kcB[1] = qA1 + qB1;
      }
#pragma unroll
      for (int g = 0; g < 2; ++g) {
        const f32x4* kc = (g == 0) ? kcA : kcB;
#pragma unroll
        for (int r = 0; r < 4; ++r) {
          float yn2[2];
#pragma unroll
          for (int tc = 0; tc < 2; ++tc) {
            const float kv = kc[tc][r] + b2v[tc];
            float yn;
            if (st == 0)      { yac[g][tc][r] = fmaf(c16, kv, y0[g][tc][r]);  yn = fmaf(ch, kv, y0[g][tc][r]); }
            else if (st == 1) { yac[g][tc][r] = fmaf(c13, kv, yac[g][tc][r]); yn = fmaf(ch, kv, y0[g][tc][r]); }
            else if (st == 2) { yac[g][tc][r] = fmaf(c13, kv, yac[g][tc][r]); yn = fmaf(dt, kv, y0[g][tc][r]); }
            else              { y0[g][tc][r]  = fmaf(c16, kv, yac[g][tc][r]); yn = y0[g][tc][r]; }
            yn2[tc] = yn;
          }
          const unsigned p = cvtpk(yn2[0], yn2[1]);
          *(unsigned short*)(sY[g] + cOff[0][r]) = (unsigned short)p;
          *(unsigned short*)(sY[g] + cOff[1][r]) = (unsigned short)(p >> 16);
        }
      }
      lds_barrier();
    }
    {  // export y_{s+1} for both groups (off-chain stores)
      const int i = tid * 8;
      const int row = i >> 7;
#pragma unroll
      for (int g = 0; g < 2; ++g) {
        const s16x8 v = *(const s16x8*)(sY[g] + swz(row, (i & 127) * 2));
        *(s16x8*)(zbuf + (long)(s + 1) * 131072 + (rowbase + g * 16) * 128 + i) = v;
      }
    }
    t_cur = t_next; t_next = t_next2;
  }
  // XW epilogue: y_final (regs, both groups) -> sYf -> XW4 rows (32 t's)
#pragma unroll
  for (int g = 0; g < 2; ++g)
#pragma unroll
    for (int tc = 0; tc < 2; ++tc)
#pragma unroll
      for (int r = 0; r < 4; ++r)
        sYf[(g * 16 + l4 * 4 + r) * 128 + colbase + 16 * tc + l15] = y0[g][tc][r];
  lds_barrier();
  {
    const int gr = tid;                    // 0..255 (gate row)
    const int q = gr >> 6, j = gr & 63;
#pragma unroll 4
    for (int tl = 0; tl < 32; ++tl) {
      float a0 = 0.f, a1 = 0.f, a2 = 0.f, a3 = 0.f;
#pragma unroll 8
      for (int k = 0; k < 32; ++k) {
        float4 wv = *(const float4*)(wih + gr * 128 + 4 * k);
        float4 yv = *(const float4*)(sYf + tl * 128 + 4 * k);
        a0 = fmaf(wv.x, yv.x, a0); a1 = fmaf(wv.y, yv.y, a1);
        a2 = fmaf(wv.z, yv.z, a2); a3 = fmaf(wv.w, yv.w, a3);
      }
      XW4[(rowbase + tl) * 256 + j * 4 + q] = bih[gr] + bhh[gr] + ((a0 + a1) + (a2 + a3));
    }
  }
}

// ---------------------------------------------------------------------------
// Kernel 2: Wf[o][k] = sum_h h2o[o][h]*l2h[h][k]; bfused[o] = h2o[o].l2h_b + h2o_b[o]
// ---------------------------------------------------------------------------
__global__ __launch_bounds__(128) void wf_kernel(
    const float* __restrict__ h2o, const float* __restrict__ l2h,
    const float* __restrict__ l2hb, const float* __restrict__ h2ob,
    unsigned short* __restrict__ wfo, float* __restrict__ bfo)
{
  const int o = (int)blockIdx.x, k = (int)threadIdx.x;
  float acc = 0.f;
  for (int h = 0; h < 256; ++h) acc = fmaf(h2o[o * 256 + h], l2h[h * 128 + k], acc);
  wfo[o * 128 + k] = f2bf(acc);
  __shared__ float red[128];
  red[k] = h2o[o * 256 + k] * l2hb[k] + h2o[o * 256 + 128 + k] * l2hb[128 + k];
  __syncthreads();
  for (int s = 64; s > 0; s >>= 1) {
    if (k < s) red[k] += red[k + s];
    __syncthreads();
  }
  if (k == 0) bfo[o] = red[0] + h2ob[o];
}

// ---------------------------------------------------------------------------
// Fused kernel: block 0 = LSTM chain; blocks 1..2048 = proj (hidden under lstm)
// ---------------------------------------------------------------------------
__device__ __forceinline__ void proj_body(
    const unsigned short* __restrict__ zbuf, const unsigned short* __restrict__ wf,
    const float* __restrict__ bfv_, float* __restrict__ xs)
{
  const int tid = (int)threadIdx.x;
  const int w = tid >> 6, lane = tid & 63;
  const int l15 = lane & 15, l4 = lane >> 4;
  const int colbase = w * 32;
  const long rowbase = (long)(blockIdx.x - 1) * 64;

  s16x8 wff[2][4];
#pragma unroll
  for (int tc = 0; tc < 2; ++tc) {
    const int rj = colbase + 16 * tc + l15;
#pragma unroll
    for (int ks = 0; ks < 4; ++ks)
      wff[tc][ks] = *(const s16x8*)(wf + rj * 128 + ks * 32 + l4 * 8);
  }
  const float bv0 = bfv_[colbase + l15], bv1 = bfv_[colbase + 16 + l15];

  const f32x4 fz = {0.f, 0.f, 0.f, 0.f};
  f32x4 acc[4][2];
#pragma unroll
  for (int rt = 0; rt < 4; ++rt) { acc[rt][0] = fz; acc[rt][1] = fz; }

#pragma unroll
  for (int rt = 0; rt < 4; ++rt) {
    const long rb = rowbase + rt * 16 + l15;
#pragma unroll
    for (int ks = 0; ks < 4; ++ks) {
      const s16x8 a = *(const s16x8*)(zbuf + rb * 128 + ks * 32 + l4 * 8);
      acc[rt][0] = MFMA16(a, wff[0][ks], acc[rt][0]);
      acc[rt][1] = MFMA16(a, wff[1][ks], acc[rt][1]);
    }
  }
#pragma unroll
  for (int rt = 0; rt < 4; ++rt)
#pragma unroll
    for (int r = 0; r < 4; ++r) {
      const long row = rowbase + rt * 16 + l4 * 4 + r;
      xs[row * 128 + colbase + l15]      = acc[rt][0][r] + bv0;
      xs[row * 128 + colbase + 16 + l15] = acc[rt][1][r] + bv1;
    }
}

// LSTM chain — 4 waves, one gate per lane; DPP quad_perm gather; 8 acc chains.
__device__ __forceinline__ void lstm_body(
    const float* __restrict__ XW4,   // [1024][64*4] (j*4+q)
    const float* __restrict__ whh,   // [256][64] f32
    float* __restrict__ hsT)         // [64][1024]
{
  const int tid = (int)threadIdx.x;  // 0..255
  const int L = tid & 63;
  const int q = L & 3;
  const int j = (tid >> 6) * 16 + (L >> 2);
  const int row = q * 64 + j;

  __shared__ __align__(16) _Float16 hbuf[2][64];

  f16x8 wq[8];                       // 64 f16 = 32 VGPR
#pragma unroll
  for (int k = 0; k < 8; ++k) wq[k] = cvt8(whh + row * 64 + 8 * k);

  // unified activation: act = A * rcp(1 + exp(S*x)) + B ; q==2 (g) is tanh
  const float Aa = (q == 2) ? 2.f : 1.f;
  const float Sa = (q == 2) ? -2.f : -1.f;
  const float Ba = (q == 2) ? -1.f : 0.f;

  if (tid < 64) hbuf[0][tid] = (_Float16)0.f;
  float c = 0.f;

  const int xwi = j * 4 + q;
  float xq[4];
#pragma unroll
  for (int i = 0; i < 4; ++i) xq[i] = XW4[i * 256 + xwi];
  lds_barrier();

  for (int tb = 0; tb < 256; ++tb) {
#pragma unroll
    for (int i = 0; i < 4; ++i) {
      const int t = tb * 4 + i;
      const int cur = i & 1;               // == t & 1
      const float xw = xq[i];
      xq[i] = XW4[((t + 4) & 1023) * 256 + xwi];  // prefetch 4 steps ahead

      const f16x8* hb8 = (const f16x8*)hbuf[cur];
      float4 ac0 = {0.f, 0.f, 0.f, 0.f}, ac1 = {0.f, 0.f, 0.f, 0.f};
#pragma unroll
      for (int r = 0; r < 8; ++r) {
        const f16x8 v = hb8[r];            // broadcast ds_read_b128
        float4& ac = (r & 1) ? ac1 : ac0;  // 8 independent dep-chains (4-deep)
        ac.x = __builtin_amdgcn_fdot2(__builtin_shufflevector(wq[r], wq[r], 0, 1),
                                      __builtin_shufflevector(v, v, 0, 1), ac.x, false);
        ac.y = __builtin_amdgcn_fdot2(__builtin_shufflevector(wq[r], wq[r], 2, 3),
                                      __builtin_shufflevector(v, v, 2, 3), ac.y, false);
        ac.z = __builtin_amdgcn_fdot2(__builtin_shufflevector(wq[r], wq[r], 4, 5),
                                      __builtin_shufflevector(v, v, 4, 5), ac.z, false);
        ac.w = __builtin_amdgcn_fdot2(__builtin_shufflevector(wq[r], wq[r], 6, 7),
                                      __builtin_shufflevector(v, v, 6, 7), ac.w, false);
      }
      const float pre = xw + (((ac0.x + ac0.y) + (ac0.z + ac0.w)) +
                              ((ac1.x + ac1.y) + (ac1.z + ac1.w)));
      const float act = fmaf(Aa, __builtin_amdgcn_rcpf(1.f + __expf(Sa * pre)), Ba);

      // gather quad's 4 gates via DPP quad_perm (VALU, no LDS pipe):
      const int ai = __float_as_int(act);
      const float x1 = __int_as_float(__builtin_amdgcn_mov_dpp(ai, 0xB1, 0xF, 0xF, true));
      const float x2 = __int_as_float(__builtin_amdgcn_mov_dpp(ai, 0x4E, 0xF, 0xF, true));
      const float x3 = __int_as_float(__builtin_amdgcn_mov_dpp(ai, 0x1B, 0xF, 0xF, true));
      const float gi = (q == 0) ? act : (q == 1) ? x1 : (q == 2) ? x2 : x3;
      const float gf = (q == 0) ? x1 : (q == 1) ? act : (q == 2) ? x3 : x2;
      const float gg = (q == 0) ? x2 : (q == 1) ? x3 : (q == 2) ? act : x1;
      const float go = (q == 0) ? x3 : (q == 1) ? x2 : (q == 2) ? x1 : act;

      c = fmaf(gf, c, gi * gg);            // identical in all 4 quad lanes
      const float th = fmaf(2.f, __builtin_amdgcn_rcpf(1.f + __expf(-2.f * c)), -1.f);
      const float h = go * th;

      if (q == 0) {
        hbuf[cur ^ 1][j] = (_Float16)h;    // next step's broadcast source
        hsT[j * 1024 + t] = h;
      }
      lds_barrier();                       // ONE barrier per step
    }
  }
}

__global__ __launch_bounds__(256, 1) void proj_lstm_kernel(
    const unsigned short* __restrict__ zbuf, const unsigned short* __restrict__ wf,
    const float* __restrict__ bfv_, float* __restrict__ xs,
    const float* __restrict__ XW4, const float* __restrict__ whh,
    float* __restrict__ hsT)
{
  if (blockIdx.x == 0) lstm_body(XW4, whh, hsT);
  else                 proj_body(zbuf, wf, bfv_, xs);
}

// ---------------------------------------------------------------------------
// Kernel 4: lstm_out[t][n] = fc2_w[n] . h_t + fc2_b[n]
// ---------------------------------------------------------------------------
__global__ __launch_bounds__(256) void fc2_kernel(
    const float* __restrict__ hsT, const float* __restrict__ fw,
    const float* __restrict__ fb, float* __restrict__ lout)
{
  const int idx = (int)blockIdx.x * 256 + (int)threadIdx.x;  // 0..2047
  const int n = idx >> 10, t = idx & 1023;
  float acc = fb[n];
#pragma unroll 8
  for (int j = 0; j < 64; ++j) acc = fmaf(fw[n * 64 + j], hsT[j * 1024 + t], acc);
  lout[t * 2 + n] = acc;
}

// ---------------------------------------------------------------------------
extern "C" void kernel_launch(void* const* d_in, const int* in_sizes, int n_in,
                              void* d_out, int out_size, void* d_ws, size_t ws_size,
                              hipStream_t stream) {
  const float* init  = (const float*)d_in[0];
  const float* ts    = (const float*)d_in[1];
  const float* ode_w1 = (const float*)d_in[2];
  const float* ode_b1 = (const float*)d_in[3];
  const float* ode_w2 = (const float*)d_in[4];
  const float* ode_b2 = (const float*)d_in[5];
  const float* l2h_w = (const float*)d_in[6];
  const float* l2h_b = (const float*)d_in[7];
  const float* h2o_w = (const float*)d_in[8];
  const float* h2o_b = (const float*)d_in[9];
  const float* wih   = (const float*)d_in[10];
  const float* whh   = (const float*)d_in[11];
  const float* bih   = (const float*)d_in[12];
  const float* bhh   = (const float*)d_in[13];
  const float* fc2w  = (const float*)d_in[14];
  const float* fc2b  = (const float*)d_in[15];

  char* ws = (char*)d_ws;
  unsigned short* zbuf  = (unsigned short*)(ws);               // 33,554,432 B
  float* XW4            = (float*)(ws + 33554432);             //  1,048,576 B
  float* hsT            = (float*)(ws + 34603008);             //    262,144 B
  unsigned short* wfbuf = (unsigned short*)(ws + 34865152);    //     32,768 B
  float* bfused         = (float*)(ws + 34897920);             //        512 B

  float* xs   = (float*)d_out;
  float* lout = xs + 16777216;

  ode_kernel<<<32, 256, 0, stream>>>(init, ts, ode_w1, ode_b1, ode_w2, ode_b2,
                                     wih, bih, bhh, zbuf, XW4);
  wf_kernel<<<128, 128, 0, stream>>>(h2o_w, l2h_w, l2h_b, h2o_b, wfbuf, bfused);
  proj_lstm_kernel<<<2049, 256, 0, stream>>>(zbuf, wfbuf, bfused, xs, XW4, whh, hsT);
  fc2_kernel<<<8, 256, 0, stream>>>(hsT, fc2w, fc2b, lout);
}

// Round 19
// 706.130 us; speedup vs baseline: 1.3909x; 1.3909x over previous
//
#include <hip/hip_runtime.h>

// B=1024, T=128, LAT=128, HODE=128, HID=256, OUT=128, NC=2, H=64.
// d_out = xs [128,1024,128] f32 ++ lstm_out [1024,2] f32.
//
// Structure (R19 = R16, measured best 706us):
//   ode  : RK4 chains + per-step bf16 y export (zbuf) + fused XW epilogue.
//          &15 swizzle (conflict-free C-writes), cvt_pk bf16 packing,
//          lgkm-only barriers, 64 blocks x 16 rows (wall = one block's chain).
//   wf   : fuse l2h*h2o -> Wf (bf16) + bfused  (overlaps ode)
//   proj_lstm : block 0 = 4-wave LSTM chain (DPP quad_perm gather);
//               blocks 1..2048 = xs = zbuf @ Wf^T + bf (hidden under lstm)
//   fc2  : tiny epilogue

typedef short s16x8 __attribute__((ext_vector_type(8)));
typedef float f32x4 __attribute__((ext_vector_type(4)));
typedef _Float16 f16x2 __attribute__((ext_vector_type(2)));
typedef _Float16 f16x8 __attribute__((ext_vector_type(8)));

#define MFMA16(a, b, c) __builtin_amdgcn_mfma_f32_16x16x32_bf16((a), (b), (c), 0, 0, 0)

// Barrier that waits only on LDS ops (lgkmcnt), NOT vmcnt (keeps global ops in flight).
__device__ __forceinline__ void lds_barrier() {
  asm volatile("s_waitcnt lgkmcnt(0)\n\ts_barrier" ::: "memory");
}

__device__ __forceinline__ unsigned short f2bf(float x) {
  union { float f; unsigned u; } v; v.f = x;
  return (unsigned short)((v.u + 0x7FFFu + ((v.u >> 16) & 1u)) >> 16);  // RNE
}

// Pack 2 f32 -> 2 bf16 in one dword (RNE; bit-identical to f2bf for finite vals).
__device__ __forceinline__ unsigned cvtpk(float lo, float hi) {
  unsigned r;
  asm("v_cvt_pk_bf16_f32 %0, %1, %2" : "=v"(r) : "v"(lo), "v"(hi));
  return r;
}

// Nibble-XOR swizzled LDS byte offset for a [16][128] bf16 tile (row stride 256B).
// Full-row-nibble XOR (&15) -> conflict-free b16 C-writes, reads <=2-way (free).
__device__ __forceinline__ int swz(int row, int col2) {
  return row * 256 + (col2 ^ ((row & 15) << 4));
}

__device__ __forceinline__ f16x8 cvt8(const float* p) {
  float4 a = *(const float4*)p, b = *(const float4*)(p + 4);
  return (f16x8){(_Float16)a.x, (_Float16)a.y, (_Float16)a.z, (_Float16)a.w,
                 (_Float16)b.x, (_Float16)b.y, (_Float16)b.z, (_Float16)b.w};
}

// ---------------------------------------------------------------------------
// Kernel 1: RK4 ODE. 64 blocks x 16 rows, 256 thr (4 waves).
// ---------------------------------------------------------------------------
__global__ __launch_bounds__(256, 1) void ode_kernel(
    const float* __restrict__ init, const float* __restrict__ ts,
    const float* __restrict__ w1, const float* __restrict__ b1,
    const float* __restrict__ w2, const float* __restrict__ b2,
    const float* __restrict__ wih, const float* __restrict__ bih,
    const float* __restrict__ bhh,
    unsigned short* __restrict__ zbuf, float* __restrict__ XW4)
{
  __shared__ __align__(16) unsigned char sY[4096];  // 16 x 128 bf16, swizzled
  __shared__ __align__(16) unsigned char sH[4096];
  __shared__ __align__(16) float sYf[2048];         // 16 x 128 f32 (XW epilogue)
  const int tid = (int)threadIdx.x;
  const int w = tid >> 6, lane = tid & 63;
  const int l15 = lane & 15, l4 = lane >> 4;
  const int rowbase = (int)blockIdx.x * 16;
  const int colbase = w * 32;

  s16x8 w1f[2][4], w2f[2][4];
#pragma unroll
  for (int tc = 0; tc < 2; ++tc) {
    const int rj = colbase + 16 * tc + l15;
#pragma unroll
    for (int ks = 0; ks < 4; ++ks) {
      const int kb = ks * 32 + l4 * 8;
      s16x8 va, vb;
#pragma unroll
      for (int t = 0; t < 8; ++t) {
        va[t] = (short)f2bf(w1[rj * 128 + kb + t]);
        vb[t] = (short)f2bf(w2[rj * 128 + kb + t]);
      }
      w1f[tc][ks] = va; w2f[tc][ks] = vb;
    }
  }
  float b1v[2], b2v[2];
#pragma unroll
  for (int tc = 0; tc < 2; ++tc) {
    const int cc = colbase + 16 * tc + l15;
    b1v[tc] = b1[cc]; b2v[tc] = b2[cc];
  }

  int aOff[4];
#pragma unroll
  for (int ks = 0; ks < 4; ++ks) aOff[ks] = swz(l15, (ks * 32 + l4 * 8) * 2);
  int cOff[2][4];
#pragma unroll
  for (int tc = 0; tc < 2; ++tc)
#pragma unroll
    for (int r = 0; r < 4; ++r)
      cOff[tc][r] = swz(l4 * 4 + r, (colbase + 16 * tc + l15) * 2);

  float y0[2][4], yac[2][4];
#pragma unroll
  for (int tc = 0; tc < 2; ++tc)
#pragma unroll
    for (int r = 0; r < 4; ++r)
      y0[tc][r] = init[(rowbase + l4 * 4 + r) * 128 + colbase + 16 * tc + l15];

  {  // stage initial y into sY + export zs slice 0
    const int i = tid * 8;
    const int row = i >> 7, col = i & 127;
    union { unsigned short u[8]; s16x8 v; } p;
#pragma unroll
    for (int t = 0; t < 8; ++t) p.u[t] = f2bf(init[(rowbase + row) * 128 + col + t]);
    *(s16x8*)(sY + swz(row, col * 2)) = p.v;
    *(s16x8*)(zbuf + rowbase * 128 + i) = p.v;
  }
  __syncthreads();

  const f32x4 fz = {0.f, 0.f, 0.f, 0.f};

  for (int s = 0; s < 127; ++s) {
    const float dt = ts[s + 1] - ts[s];
    const float c16 = dt * (1.f / 6.f), c13 = dt * (1.f / 3.f), ch = dt * 0.5f;
#pragma unroll
    for (int st = 0; st < 4; ++st) {
      f32x4 acc[2];
      acc[0] = fz; acc[1] = fz;
#pragma unroll
      for (int ks = 0; ks < 4; ++ks) {
        s16x8 a = *(const s16x8*)(sY + aOff[ks]);
        acc[0] = MFMA16(a, w1f[0][ks], acc[0]);
        acc[1] = MFMA16(a, w1f[1][ks], acc[1]);
      }
      // bias + ELU + packed bf16 store
#pragma unroll
      for (int r = 0; r < 4; ++r) {
        float v0 = acc[0][r] + b1v[0];
        float v1 = acc[1][r] + b1v[1];
        v0 = v0 > 0.f ? v0 : (__expf(v0) - 1.f);  // ELU (alpha=1)
        v1 = v1 > 0.f ? v1 : (__expf(v1) - 1.f);
        const unsigned p = cvtpk(v0, v1);
        *(unsigned short*)(sH + cOff[0][r]) = (unsigned short)p;
        *(unsigned short*)(sH + cOff[1][r]) = (unsigned short)(p >> 16);
      }
      lds_barrier();
      f32x4 kc[2];
      kc[0] = fz; kc[1] = fz;
#pragma unroll
      for (int ks = 0; ks < 4; ++ks) {
        s16x8 a = *(const s16x8*)(sH + aOff[ks]);
        kc[0] = MFMA16(a, w2f[0][ks], kc[0]);
        kc[1] = MFMA16(a, w2f[1][ks], kc[1]);
      }
#pragma unroll
      for (int r = 0; r < 4; ++r) {
        float yn2[2];
#pragma unroll
        for (int tc = 0; tc < 2; ++tc) {
          const float kv = kc[tc][r] + b2v[tc];
          float yn;
          if (st == 0)      { yac[tc][r] = fmaf(c16, kv, y0[tc][r]);  yn = fmaf(ch, kv, y0[tc][r]); }
          else if (st == 1) { yac[tc][r] = fmaf(c13, kv, yac[tc][r]); yn = fmaf(ch, kv, y0[tc][r]); }
          else if (st == 2) { yac[tc][r] = fmaf(c13, kv, yac[tc][r]); yn = fmaf(dt, kv, y0[tc][r]); }
          else              { y0[tc][r]  = fmaf(c16, kv, yac[tc][r]); yn = y0[tc][r]; }
          yn2[tc] = yn;
        }
        const unsigned p = cvtpk(yn2[0], yn2[1]);
        *(unsigned short*)(sY + cOff[0][r]) = (unsigned short)p;
        *(unsigned short*)(sY + cOff[1][r]) = (unsigned short)(p >> 16);
      }
      lds_barrier();
    }
    {  // export y_{s+1} (coalesced, off-chain: no vmcnt wait on the chain)
      const int i = tid * 8;
      const int row = i >> 7;
      const s16x8 v = *(const s16x8*)(sY + swz(row, (i & 127) * 2));
      *(s16x8*)(zbuf + (long)(s + 1) * 131072 + rowbase * 128 + i) = v;
    }
  }
  // XW epilogue: y_final (regs) -> sYf -> XW4 rows for this block's 16 t's
#pragma unroll
  for (int tc = 0; tc < 2; ++tc)
#pragma unroll
    for (int r = 0; r < 4; ++r)
      sYf[(l4 * 4 + r) * 128 + colbase + 16 * tc + l15] = y0[tc][r];
  lds_barrier();
  {
    const int g = tid;                     // 0..255 (gate row)
    const int q = g >> 6, j = g & 63;
#pragma unroll 4
    for (int tl = 0; tl < 16; ++tl) {
      float a0 = 0.f, a1 = 0.f, a2 = 0.f, a3 = 0.f;
#pragma unroll 8
      for (int k = 0; k < 32; ++k) {
        float4 wv = *(const float4*)(wih + g * 128 + 4 * k);
        float4 yv = *(const float4*)(sYf + tl * 128 + 4 * k);
        a0 = fmaf(wv.x, yv.x, a0); a1 = fmaf(wv.y, yv.y, a1);
        a2 = fmaf(wv.z, yv.z, a2); a3 = fmaf(wv.w, yv.w, a3);
      }
      XW4[(rowbase + tl) * 256 + j * 4 + q] = bih[g] + bhh[g] + ((a0 + a1) + (a2 + a3));
    }
  }
}

// ---------------------------------------------------------------------------
// Kernel 2: Wf[o][k] = sum_h h2o[o][h]*l2h[h][k]; bfused[o] = h2o[o].l2h_b + h2o_b[o]
// ---------------------------------------------------------------------------
__global__ __launch_bounds__(128) void wf_kernel(
    const float* __restrict__ h2o, const float* __restrict__ l2h,
    const float* __restrict__ l2hb, const float* __restrict__ h2ob,
    unsigned short* __restrict__ wfo, float* __restrict__ bfo)
{
  const int o = (int)blockIdx.x, k = (int)threadIdx.x;
  float acc = 0.f;
  for (int h = 0; h < 256; ++h) acc = fmaf(h2o[o * 256 + h], l2h[h * 128 + k], acc);
  wfo[o * 128 + k] = f2bf(acc);
  __shared__ float red[128];
  red[k] = h2o[o * 256 + k] * l2hb[k] + h2o[o * 256 + 128 + k] * l2hb[128 + k];
  __syncthreads();
  for (int s = 64; s > 0; s >>= 1) {
    if (k < s) red[k] += red[k + s];
    __syncthreads();
  }
  if (k == 0) bfo[o] = red[0] + h2ob[o];
}

// ---------------------------------------------------------------------------
// Fused kernel: block 0 = LSTM chain; blocks 1..2048 = proj (hidden under lstm)
// ---------------------------------------------------------------------------
__device__ __forceinline__ void proj_body(
    const unsigned short* __restrict__ zbuf, const unsigned short* __restrict__ wf,
    const float* __restrict__ bfv_, float* __restrict__ xs)
{
  const int tid = (int)threadIdx.x;
  const int w = tid >> 6, lane = tid & 63;
  const int l15 = lane & 15, l4 = lane >> 4;
  const int colbase = w * 32;
  const long rowbase = (long)(blockIdx.x - 1) * 64;

  s16x8 wff[2][4];
#pragma unroll
  for (int tc = 0; tc < 2; ++tc) {
    const int rj = colbase + 16 * tc + l15;
#pragma unroll
    for (int ks = 0; ks < 4; ++ks)
      wff[tc][ks] = *(const s16x8*)(wf + rj * 128 + ks * 32 + l4 * 8);
  }
  const float bv0 = bfv_[colbase + l15], bv1 = bfv_[colbase + 16 + l15];

  const f32x4 fz = {0.f, 0.f, 0.f, 0.f};
  f32x4 acc[4][2];
#pragma unroll
  for (int rt = 0; rt < 4; ++rt) { acc[rt][0] = fz; acc[rt][1] = fz; }

#pragma unroll
  for (int rt = 0; rt < 4; ++rt) {
    const long rb = rowbase + rt * 16 + l15;
#pragma unroll
    for (int ks = 0; ks < 4; ++ks) {
      const s16x8 a = *(const s16x8*)(zbuf + rb * 128 + ks * 32 + l4 * 8);
      acc[rt][0] = MFMA16(a, wff[0][ks], acc[rt][0]);
      acc[rt][1] = MFMA16(a, wff[1][ks], acc[rt][1]);
    }
  }
#pragma unroll
  for (int rt = 0; rt < 4; ++rt)
#pragma unroll
    for (int r = 0; r < 4; ++r) {
      const long row = rowbase + rt * 16 + l4 * 4 + r;
      xs[row * 128 + colbase + l15]      = acc[rt][0][r] + bv0;
      xs[row * 128 + colbase + 16 + l15] = acc[rt][1][r] + bv1;
    }
}

// LSTM chain — 4 waves, one gate per lane; DPP quad_perm gather; 8 acc chains.
__device__ __forceinline__ void lstm_body(
    const float* __restrict__ XW4,   // [1024][64*4] (j*4+q)
    const float* __restrict__ whh,   // [256][64] f32
    float* __restrict__ hsT)         // [64][1024]
{
  const int tid = (int)threadIdx.x;  // 0..255
  const int L = tid & 63;
  const int q = L & 3;
  const int j = (tid >> 6) * 16 + (L >> 2);
  const int row = q * 64 + j;

  __shared__ __align__(16) _Float16 hbuf[2][64];

  f16x8 wq[8];                       // 64 f16 = 32 VGPR
#pragma unroll
  for (int k = 0; k < 8; ++k) wq[k] = cvt8(whh + row * 64 + 8 * k);

  // unified activation: act = A * rcp(1 + exp(S*x)) + B ; q==2 (g) is tanh
  const float Aa = (q == 2) ? 2.f : 1.f;
  const float Sa = (q == 2) ? -2.f : -1.f;
  const float Ba = (q == 2) ? -1.f : 0.f;

  if (tid < 64) hbuf[0][tid] = (_Float16)0.f;
  float c = 0.f;

  const int xwi = j * 4 + q;
  float xq[4];
#pragma unroll
  for (int i = 0; i < 4; ++i) xq[i] = XW4[i * 256 + xwi];
  lds_barrier();

  for (int tb = 0; tb < 256; ++tb) {
#pragma unroll
    for (int i = 0; i < 4; ++i) {
      const int t = tb * 4 + i;
      const int cur = i & 1;               // == t & 1
      const float xw = xq[i];
      xq[i] = XW4[((t + 4) & 1023) * 256 + xwi];  // prefetch 4 steps ahead

      const f16x8* hb8 = (const f16x8*)hbuf[cur];
      float4 ac0 = {0.f, 0.f, 0.f, 0.f}, ac1 = {0.f, 0.f, 0.f, 0.f};
#pragma unroll
      for (int r = 0; r < 8; ++r) {
        const f16x8 v = hb8[r];            // broadcast ds_read_b128
        float4& ac = (r & 1) ? ac1 : ac0;  // 8 independent dep-chains (4-deep)
        ac.x = __builtin_amdgcn_fdot2(__builtin_shufflevector(wq[r], wq[r], 0, 1),
                                      __builtin_shufflevector(v, v, 0, 1), ac.x, false);
        ac.y = __builtin_amdgcn_fdot2(__builtin_shufflevector(wq[r], wq[r], 2, 3),
                                      __builtin_shufflevector(v, v, 2, 3), ac.y, false);
        ac.z = __builtin_amdgcn_fdot2(__builtin_shufflevector(wq[r], wq[r], 4, 5),
                                      __builtin_shufflevector(v, v, 4, 5), ac.z, false);
        ac.w = __builtin_amdgcn_fdot2(__builtin_shufflevector(wq[r], wq[r], 6, 7),
                                      __builtin_shufflevector(v, v, 6, 7), ac.w, false);
      }
      const float pre = xw + (((ac0.x + ac0.y) + (ac0.z + ac0.w)) +
                              ((ac1.x + ac1.y) + (ac1.z + ac1.w)));
      const float act = fmaf(Aa, __builtin_amdgcn_rcpf(1.f + __expf(Sa * pre)), Ba);

      // gather quad's 4 gates via DPP quad_perm (VALU, no LDS pipe):
      const int ai = __float_as_int(act);
      const float x1 = __int_as_float(__builtin_amdgcn_mov_dpp(ai, 0xB1, 0xF, 0xF, true));
      const float x2 = __int_as_float(__builtin_amdgcn_mov_dpp(ai, 0x4E, 0xF, 0xF, true));
      const float x3 = __int_as_float(__builtin_amdgcn_mov_dpp(ai, 0x1B, 0xF, 0xF, true));
      const float gi = (q == 0) ? act : (q == 1) ? x1 : (q == 2) ? x2 : x3;
      const float gf = (q == 0) ? x1 : (q == 1) ? act : (q == 2) ? x3 : x2;
      const float gg = (q == 0) ? x2 : (q == 1) ? x3 : (q == 2) ? act : x1;
      const float go = (q == 0) ? x3 : (q == 1) ? x2 : (q == 2) ? x1 : act;

      c = fmaf(gf, c, gi * gg);            // identical in all 4 quad lanes
      const float th = fmaf(2.f, __builtin_amdgcn_rcpf(1.f + __expf(-2.f * c)), -1.f);
      const float h = go * th;

      if (q == 0) {
        hbuf[cur ^ 1][j] = (_Float16)h;    // next step's broadcast source
        hsT[j * 1024 + t] = h;
      }
      lds_barrier();                       // ONE barrier per step
    }
  }
}

__global__ __launch_bounds__(256, 1) void proj_lstm_kernel(
    const unsigned short* __restrict__ zbuf, const unsigned short* __restrict__ wf,
    const float* __restrict__ bfv_, float* __restrict__ xs,
    const float* __restrict__ XW4, const float* __restrict__ whh,
    float* __restrict__ hsT)
{
  if (blockIdx.x == 0) lstm_body(XW4, whh, hsT);
  else                 proj_body(zbuf, wf, bfv_, xs);
}

// ---------------------------------------------------------------------------
// Kernel 4: lstm_out[t][n] = fc2_w[n] . h_t + fc2_b[n]
// ---------------------------------------------------------------------------
__global__ __launch_bounds__(256) void fc2_kernel(
    const float* __restrict__ hsT, const float* __restrict__ fw,
    const float* __restrict__ fb, float* __restrict__ lout)
{
  const int idx = (int)blockIdx.x * 256 + (int)threadIdx.x;  // 0..2047
  const int n = idx >> 10, t = idx & 1023;
  float acc = fb[n];
#pragma unroll 8
  for (int j = 0; j < 64; ++j) acc = fmaf(fw[n * 64 + j], hsT[j * 1024 + t], acc);
  lout[t * 2 + n] = acc;
}

// ---------------------------------------------------------------------------
extern "C" void kernel_launch(void* const* d_in, const int* in_sizes, int n_in,
                              void* d_out, int out_size, void* d_ws, size_t ws_size,
                              hipStream_t stream) {
  const float* init  = (const float*)d_in[0];
  const float* ts    = (const float*)d_in[1];
  const float* ode_w1 = (const float*)d_in[2];
  const float* ode_b1 = (const float*)d_in[3];
  const float* ode_w2 = (const float*)d_in[4];
  const float* ode_b2 = (const float*)d_in[5];
  const float* l2h_w = (const float*)d_in[6];
  const float* l2h_b = (const float*)d_in[7];
  const float* h2o_w = (const float*)d_in[8];
  const float* h2o_b = (const float*)d_in[9];
  const float* wih   = (const float*)d_in[10];
  const float* whh   = (const float*)d_in[11];
  const float* bih   = (const float*)d_in[12];
  const float* bhh   = (const float*)d_in[13];
  const float* fc2w  = (const float*)d_in[14];
  const float* fc2b  = (const float*)d_in[15];

  char* ws = (char*)d_ws;
  unsigned short* zbuf  = (unsigned short*)(ws);               // 33,554,432 B
  float* XW4            = (float*)(ws + 33554432);             //  1,048,576 B
  float* hsT            = (float*)(ws + 34603008);             //    262,144 B
  unsigned short* wfbuf = (unsigned short*)(ws + 34865152);    //     32,768 B
  float* bfused         = (float*)(ws + 34897920);             //        512 B

  float* xs   = (float*)d_out;
  float* lout = xs + 16777216;

  ode_kernel<<<64, 256, 0, stream>>>(init, ts, ode_w1, ode_b1, ode_w2, ode_b2,
                                     wih, bih, bhh, zbuf, XW4);
  wf_kernel<<<128, 128, 0, stream>>>(h2o_w, l2h_w, l2h_b, h2o_b, wfbuf, bfused);
  proj_lstm_kernel<<<2049, 256, 0, stream>>>(zbuf, wfbuf, bfused, xs, XW4, whh, hsT);
  fc2_kernel<<<8, 256, 0, stream>>>(hsT, fc2w, fc2b, lout);
}